// Round 1
// baseline (229.037 us; speedup 1.0000x reference)
//
#include <hip/hip_runtime.h>

#define S_DIM 26
#define NCLS 80
#define CELLS 676        // 26*26
#define NB 32
#define NCH 255          // 3*(5+80)
#define CH_BLK 85        // 5+80
#define PLANE_F4 507     // 3 * 169
#define F4_PER_PLANE 169 // 676/4
#define F4_PLANE_STRIDE 14365 // 85*676/4

#define HEAD_SCALE  (5.0f / 32.0f)    // LAMBDA_COORD * (1/NB) per squared diff
#define LABEL_SCALE (1.0f / 2560.0f)  // 1/(NB*NCLS)
#define U_SPLIT 864                   // label flat-index split: [0,864),[864,1728),[1728,2560)

// Per-box head math: returns sum of the 5 squared diffs for this box.
__device__ inline float head_terms(const float* __restrict__ xb,
                                   int off, int ni,
                                   float w, float h, float ax, float ay)
{
    float obj = xb[off];
    float rax = xb[off + 1 * CELLS];
    float ray = xb[off + 2 * CELLS];
    float t3  = xb[off + 3 * CELLS];
    float t4  = xb[off + 4 * CELLS];

    const float AW[3] = {30.f, 62.f, 59.f};   // anchors rows 3..5
    const float AH[3] = {61.f, 45.f, 119.f};
    float sig3 = 1.0f / (1.0f + expf(-t3));
    float sig4 = 1.0f / (1.0f + expf(-t4));
    float rw = AW[ni] * expf(4.0f * sig3 - 2.0f);
    float rh = AH[ni] * expf(4.0f * sig4 - 2.0f);

    float b1x0 = rax * 16.f - rw * 0.5f, b1y0 = ray * 16.f - rh * 0.5f;
    float b1x1 = rax * 16.f + rw * 0.5f, b1y1 = ray * 16.f + rh * 0.5f;
    float b2x0 = ax * 16.f - w * 0.5f,   b2y0 = ay * 16.f - h * 0.5f;
    float b2x1 = ax * 16.f + w * 0.5f,   b2y1 = ay * 16.f + h * 0.5f;
    float A  = (rw + 1.f) * (rh + 1.f);
    float Bt = (w + 1.f) * (h + 1.f);
    float CM = (fminf(b1x1, b2x1) - fmaxf(b1x0, b2x0) + 1.f) *
               (fminf(b1y1, b2y1) - fmaxf(b1y0, b2y0) + 1.f);
    float r = CM / (A + Bt - CM);
    float iou = (r < 0.f) ? 0.f : r;

    float acc = 0.f, d;
    d = obj - iou;                  acc += d * d;
    d = rax - ax;                   acc += d * d;
    d = ray - ay;                   acc += d * d;
    d = (rw - w) * (1.f / 416.f);   acc += d * d;
    d = (rh - h) * (1.f / 416.f);   acc += d * d;
    return acc;
}

// Work partition (grid = (B, 3), 256 threads):
//   all slices: box meta for all 32 boxes (tiny, L2-resident)
//   heads:  slice0 boxes [0,11), slice1 [11,22), slice2 [22,32)
//   labels: flat u=box*80+c; slice0 [0,864), slice1 [864,1728), slice2 [1728,2560)
//   planes (noobj sum-sq): slice2 only, accumulated in r1
//   dedupe: slice0 (distinct count -> r2, distinct obj^2 -> r1), slice2 (count -> r2)
__global__ __launch_bounds__(256)
void yolo_loss_v2(const float* __restrict__ x,     // (B,255,26,26)
                  const float* __restrict__ box,   // (B,32,5)
                  const int*   __restrict__ nidx,  // (B,32)
                  float* __restrict__ out)
{
    const int b     = blockIdx.x;
    const int slice = blockIdx.y;
    const int tid   = threadIdx.x;
    const float* xb = x + (size_t)b * (NCH * CELLS);

    __shared__ int   s_key[NB];
    __shared__ int   s_off[NB];
    __shared__ int   s_cls[NB];
    __shared__ float s_obj2[NB];
    __shared__ float s_red[3][4];

    float r0 = 0.f, r1 = 0.f, r2 = 0.f;

    // ---- box meta (all 32 boxes, every slice) + this slice's head terms ----
    if (tid < NB) {
        const float* bx = box + ((size_t)b * NB + tid) * 5;
        float cls = bx[0], cx = bx[1], cy = bx[2], w = bx[3], h = bx[4];
        int ni = nidx[b * NB + tid] - 3;
        int ix = (int)(cx * 0.0625f);
        int iy = (int)(cy * 0.0625f);
        float ax = (cx - (float)ix * 16.0f) * 0.0625f;
        float ay = (cy - (float)iy * 16.0f) * 0.0625f;
        int cell = ix * S_DIM + iy;
        int off  = ni * CH_BLK * CELLS + cell;
        s_key[tid] = ni * CELLS + cell;
        s_off[tid] = off;
        s_cls[tid] = (int)cls;
        if (slice == 0) s_obj2[tid] = xb[off] * xb[off];

        int h0 = slice * 11;                       // 0, 11, 22
        int h1 = (slice == 2) ? NB : (h0 + 11);    // 11, 22, 32
        if (tid >= h0 && tid < h1)
            r0 += head_terms(xb, off, ni, w, h, ax, ay) * HEAD_SCALE;
    }
    __syncthreads();

    // ---- dedupe (first-occurrence scan over 32 keys) ----
    if (tid < NB && slice != 1) {
        bool first = true;
        for (int s = 0; s < tid; ++s)
            if (s_key[s] == s_key[tid]) { first = false; break; }
        if (first) {
            r2 += 1.0f;                            // distinct-cell count
            if (slice == 0) r1 += s_obj2[tid];     // obj^2 to remove from plane sum
        }
    }

    // ---- label (class) terms: this slice's share of the 2560 scattered loads ----
    {
        int u0 = slice * U_SPLIT;
        int u1 = (slice == 2) ? (NB * NCLS) : (u0 + U_SPLIT);
        for (int u = u0 + tid; u < u1; u += 256) {
            int t = u / NCLS;                      // global box 0..31
            int c = u - t * NCLS;
            float val = xb[s_off[t] + (5 + c) * CELLS];
            float hot = (c == s_cls[t]) ? 1.0f : 0.0f;
            float d = val - hot;
            r0 += d * d * LABEL_SCALE;
        }
    }

    // ---- noobj plane sum of squares (slice2 only), float4 coalesced ----
    if (slice == 2) {
        const float4* p4 = (const float4*)xb;
        for (int u = tid; u < PLANE_F4; u += 256) {
            int pl = (u >= 2 * F4_PER_PLANE) ? 2 : (u >= F4_PER_PLANE ? 1 : 0);
            int i4 = u - pl * F4_PER_PLANE;
            float4 v = p4[pl * F4_PLANE_STRIDE + i4];
            r1 += v.x * v.x + v.y * v.y + v.z * v.z + v.w * v.w;
        }
    }

    // ---- block reduction of r0, r1, r2 (4 waves of 64) ----
    #pragma unroll
    for (int o = 32; o > 0; o >>= 1) {
        r0 += __shfl_down(r0, o, 64);
        r1 += __shfl_down(r1, o, 64);
        r2 += __shfl_down(r2, o, 64);
    }
    int wave = tid >> 6;
    if ((tid & 63) == 0) { s_red[0][wave] = r0; s_red[1][wave] = r1; s_red[2][wave] = r2; }
    __syncthreads();
    if (tid == 0) {
        float t0 = s_red[0][0] + s_red[0][1] + s_red[0][2] + s_red[0][3];
        float t1 = s_red[1][0] + s_red[1][1] + s_red[1][2] + s_red[1][3];
        float t2 = s_red[2][0] + s_red[2][1] + s_red[2][2] + s_red[2][3];
        float contrib;
        if (slice == 0) {
            float cnt = 2028.0f - t2;              // 3*676 - distinct boxes
            contrib = t0 - 0.5f * t1 / cnt;        // heads+labels - obj^2 correction
        } else if (slice == 1) {
            contrib = t0;                          // heads+labels only
        } else {
            float cnt = 2028.0f - t2;
            contrib = t0 + 0.5f * t1 / cnt;        // heads+labels + LAMBDA_NOOBJ*plane/cnt
        }
        atomicAdd(out, contrib);
    }
}

extern "C" void kernel_launch(void* const* d_in, const int* in_sizes, int n_in,
                              void* d_out, int out_size, void* d_ws, size_t ws_size,
                              hipStream_t stream) {
    const float* x    = (const float*)d_in[0];
    const float* box  = (const float*)d_in[1];
    const int*   nidx = (const int*)d_in[2];
    float* out = (float*)d_out;

    hipMemsetAsync(out, 0, sizeof(float) * out_size, stream);
    yolo_loss_v2<<<dim3(256, 3), dim3(256), 0, stream>>>(x, box, nidx, out);
}